// Round 12
// baseline (25670.755 us; speedup 1.0000x reference)
//
#include <hip/hip_runtime.h>

// MatchLSTM forward (Round 12) = Round 11 resubmitted verbatim (Round-11
// bench died to infra: "MI355X container failed twice" — same as Round 8,
// where identical resubmission then passed; hypothesis untested, so re-run).
//
// Round-10 counters: phaseB 30 us/step, VALUBusy 40%, FETCH 59MB (weights
// L2-resident; nontemporal activation loads worked). Remaining stall: the
// unroll-1 chunk loops serialize load-wait-compute. Fix: double-buffered
// 8x uint4 staging (ping-pong uA/uB), load chunk c+1 while computing c;
// VGPR budget ~104 < 128/wave ceiling at 1024 threads (spill check:
// WRITE_SIZE must stay ~KB).
//
// Structure: phase B independent per batch element (one block per b, 1024
// threads, K-split GEMVs, LDS reductions, no grid sync). Phase A = 5 fp32
// tiled GEMMs (unchanged).

#define DEV static __device__ __forceinline__

DEV float fast_sigmoid(float x) { return 1.0f / (1.0f + __expf(-x)); }
DEV float fast_tanh(float x)    { return 1.0f - 2.0f / (__expf(2.0f * x) + 1.0f); }

// bf16 pack/unpack (RTNE pack; unpack = shift into fp32 exponent position)
DEV unsigned f2bf(float x) {
    unsigned v = __float_as_uint(x);
    return (v + 0x7FFFu + ((v >> 16) & 1u)) >> 16;
}
DEV float blo(unsigned u) { return __uint_as_float(u << 16); }
DEV float bhi(unsigned u) { return __uint_as_float(u & 0xFFFF0000u); }

DEV float ntload(const float* p) { return __builtin_nontemporal_load(p); }

// ---------------------------------------------------------------------------
// Phase A GEMM (unchanged from Round 1; verified passing).
// ---------------------------------------------------------------------------
template<int BM, int NG, int MODE, int GATHER>
__global__ __launch_bounds__(256) void gemm3_kernel(
    const float* __restrict__ A, const int* __restrict__ gidx, int lda,
    const float* __restrict__ W, int ldw, int K,
    const float* __restrict__ bias1, const float* __restrict__ bias2,
    const float* __restrict__ add3, float* __restrict__ out)
{
    constexpr int BK = 32;
    constexpr int TM = BM / 16;
    constexpr int TJ = 2;
    constexpr int AP = BM + 4;
    constexpr int WP = NG * 32 + 4;
    __shared__ __align__(16) float As[BK][AP];
    __shared__ __align__(16) float Wsh[BK][WP];

    const int tid = threadIdx.x;
    const int ty = tid >> 4;
    const int tx = tid & 15;
    const int m0 = blockIdx.x * BM;
    const int j0 = blockIdx.y * 32;

    float acc[TM][TJ][NG];
#pragma unroll
    for (int im = 0; im < TM; ++im)
#pragma unroll
        for (int ij = 0; ij < TJ; ++ij)
#pragma unroll
            for (int g = 0; g < NG; ++g) acc[im][ij][g] = 0.0f;

    for (int k0 = 0; k0 < K; k0 += BK) {
#pragma unroll
        for (int i = tid; i < BM * BK; i += 256) {
            int r = i >> 5, c = i & 31;
            int gk = k0 + c;
            float v = 0.0f;
            if (gk < K) {
                int arow = GATHER ? gidx[m0 + r] : (m0 + r);
                v = A[arow * lda + gk];
            }
            As[c][r] = v;
        }
#pragma unroll
        for (int i = tid; i < NG * 32 * BK; i += 256) {
            int rl = i >> 5, c = i & 31;
            int g = rl >> 5, jj = rl & 31;
            int row = (g == 0 ? 0 : (g == 1 ? 1024 : 1536)) + j0 + jj;
            int gk = k0 + c;
            float v = (gk < K) ? W[row * ldw + gk] : 0.0f;
            Wsh[c][rl] = v;
        }
        __syncthreads();
#pragma unroll
        for (int kk = 0; kk < BK; ++kk) {
            float av[TM];
            if constexpr (TM == 4) {
                float4 t4 = *reinterpret_cast<const float4*>(&As[kk][ty * 4]);
                av[0] = t4.x; av[1] = t4.y; av[2] = t4.z; av[3] = t4.w;
            } else {
                float2 t2 = *reinterpret_cast<const float2*>(&As[kk][ty * 2]);
                av[0] = t2.x; av[1] = t2.y;
            }
#pragma unroll
            for (int g = 0; g < NG; ++g) {
                float2 w2 = *reinterpret_cast<const float2*>(&Wsh[kk][g * 32 + tx * 2]);
#pragma unroll
                for (int im = 0; im < TM; ++im) {
                    acc[im][0][g] += av[im] * w2.x;
                    acc[im][1][g] += av[im] * w2.y;
                }
            }
        }
        __syncthreads();
    }

#pragma unroll
    for (int im = 0; im < TM; ++im) {
        int m = m0 + ty * TM + im;
#pragma unroll
        for (int ij = 0; ij < TJ; ++ij) {
            int j = j0 + tx * TJ + ij;
            if constexpr (MODE == 3) {
                out[m * 512 + j] = acc[im][ij][0];
            } else if constexpr (MODE == 1) {
                out[(m * 3 + 0) * 512 + j] = acc[im][ij][0] + bias1[j] + bias2[j];
                out[(m * 3 + 1) * 512 + j] = acc[im][ij][1] + bias1[1024 + j] + bias2[1024 + j];
                out[(m * 3 + 2) * 512 + j] = acc[im][ij][2] + bias1[1536 + j] + bias2[1536 + j];
            } else if constexpr (MODE == 0) {
                float gi = acc[im][ij][0] + bias1[j] + bias2[j];
                float gg = acc[im][ij][1] + bias1[1024 + j] + bias2[1024 + j];
                float go = acc[im][ij][2] + bias1[1536 + j] + bias2[1536 + j];
                float c  = fast_sigmoid(gi) * fast_tanh(gg);
                out[m * 512 + j] = fast_sigmoid(go) * fast_tanh(c);
            } else {
                float gi = acc[im][ij][0] + add3[(m * 3 + 0) * 512 + j];
                float gg = acc[im][ij][1] + add3[(m * 3 + 1) * 512 + j];
                float go = acc[im][ij][2] + add3[(m * 3 + 2) * 512 + j];
                float c  = fast_sigmoid(gi) * fast_tanh(gg);
                out[m * 512 + j] = fast_sigmoid(go) * fast_tanh(c);
            }
        }
    }
}

// ---------------------------------------------------------------------------
// Transpose + bf16-pack into uint4 layout (verified, absmax 9.8e-4):
//   uint4 Wpk[h/8][cols]; [hq][col] packs W[col][8hq..8hq+7] as 4 bf16-pair
//   dwords. dword index for pair q=(h/2), col: (q>>2)*(4*out_ld)+4*col+(q&3).
// ---------------------------------------------------------------------------
__global__ __launch_bounds__(256) void trans_pack_kernel(
    const float* __restrict__ W, int ld, int gates,
    unsigned* __restrict__ out, int out_ld)
{
    __shared__ float tile[64][129];
    const int j0 = blockIdx.x * 64;
    const int h0 = blockIdx.y * 128;
    const int g  = blockIdx.z;
    const int row_base = gates ? (g == 0 ? 0 : (g == 1 ? 1024 : 1536)) : 0;
    const int out_col  = gates ? g * 512 : 0;

    for (int i = threadIdx.x; i < 64 * 128; i += 256) {
        int jj = i >> 7, hh = i & 127;
        tile[jj][hh] = W[(size_t)(row_base + j0 + jj) * ld + h0 + hh];
    }
    __syncthreads();
    for (int i = threadIdx.x; i < 4096; i += 256) {
        int jj = i & 63, q = i >> 6;
        int gq = h0 / 2 + q;
        unsigned lo = f2bf(tile[jj][2 * q]);
        unsigned hi = f2bf(tile[jj][2 * q + 1]);
        int col = out_col + j0 + jj;
        out[(size_t)(gq >> 2) * (4 * out_ld) + 4 * col + (gq & 3)] = lo | (hi << 16);
    }
}

// ---- software-pipeline building blocks -----------------------------------
DEV void ldc8(uint4* u, const uint4* wp, int row0, int stride_u4)
{
#pragma unroll
    for (int z = 0; z < 8; ++z) u[z] = wp[(size_t)(row0 + z) * stride_u4];
}

DEV float dotc8(const uint4* u, const float* v)
{
    float p = 0.0f;
#pragma unroll
    for (int z = 0; z < 8; ++z) {
        float4 vA = *(const float4*)&v[z * 8];
        float4 vB = *(const float4*)&v[z * 8 + 4];
        p += blo(u[z].x) * vA.x + bhi(u[z].x) * vA.y
           + blo(u[z].y) * vA.z + bhi(u[z].y) * vA.w
           + blo(u[z].z) * vB.x + bhi(u[z].z) * vB.y
           + blo(u[z].w) * vB.z + bhi(u[z].w) * vB.w;
    }
    return p;
}

// ---------------------------------------------------------------------------
// Phase B: one block per batch element b, 1024 threads, 64 steps, no grid
// sync. Thread = (kh = tid>>9, j = tid&511); every GEMV K-split across the
// two halves with an LDS partial reduction. Weight GEMVs double-buffered:
// load chunk c+1 while computing chunk c (8+8 uint4 in flight).
// ---------------------------------------------------------------------------
__global__ __launch_bounds__(1024) void phaseB_kernel(
    const float* __restrict__ pre_s, const float* __restrict__ pre_t,
    const float* __restrict__ h_s,   const float* __restrict__ pre_m_h,
    const unsigned* __restrict__ WmT2, const unsigned* __restrict__ W3t2,
    const float* __restrict__ w_e,
    const float* __restrict__ fc_w,  const float* __restrict__ fc_b,
    float* __restrict__ out)
{
    __shared__ __align__(16) float hm[512];
    __shared__ __align__(16) float av[512];
    __shared__ __align__(16) float base[512];
    __shared__ __align__(16) float wesh[512];
    __shared__ __align__(16) float sc[64];
    __shared__ __align__(16) float red[2 * 512];       //  4 KB
    __shared__ __align__(16) float red3[3 * 2 * 512];  // 12 KB

    const int b    = blockIdx.x;
    const int tid  = threadIdx.x;          // 0..1023
    const int wv   = tid >> 6;             // 0..15
    const int lane = tid & 63;
    const int j    = tid & 511;            // output column
    const int kh   = tid >> 9;             // K-half (0/1)
    const int hq0  = kh * 32;              // this half's packed-row base

    if (tid < 512) { wesh[tid] = w_e[tid]; hm[tid] = 0.0f; }
    __syncthreads();

    const uint4* wpm = (const uint4*)WmT2 + j;   // [64][512]  uint4 view
    const uint4* wp3 = (const uint4*)W3t2 + j;   // [64][1536] uint4 view

    for (int k = 0; k < 64; ++k) {
        // ---- wm partials (pipelined): red[kh][j] = hm[khalf].Wm[j][khalf]
        if (k > 0) {
            uint4 uA[8], uB[8];
            ldc8(uA, wpm, hq0 +  0, 512);
            ldc8(uB, wpm, hq0 +  8, 512);
            float p = dotc8(uA, &hm[(hq0 + 0) * 8]);
            ldc8(uA, wpm, hq0 + 16, 512);
            p += dotc8(uB, &hm[(hq0 +  8) * 8]);
            ldc8(uB, wpm, hq0 + 24, 512);
            p += dotc8(uA, &hm[(hq0 + 16) * 8]);
            p += dotc8(uB, &hm[(hq0 + 24) * 8]);
            red[kh * 512 + j] = p;
        }
        __syncthreads();
        if (tid < 512) {
            float wmj = (k > 0) ? (red[tid] + red[512 + tid]) : 0.0f;
            base[tid] = ntload(&pre_t[((size_t)k * 128 + b) * 512 + tid]) + wmj;
        }
        __syncthreads();

        // ---- scores: wave wv handles t = wv*4 .. wv*4+3 ----
#pragma unroll
        for (int tt = 0; tt < 4; ++tt) {
            int t = wv * 4 + tt;
            const float* ps = pre_s + ((size_t)t * 128 + b) * 512;
            float p = 0.0f;
#pragma unroll
            for (int u = 0; u < 8; ++u) {
                int h = lane + 64 * u;
                p += wesh[h] * fast_tanh(ntload(&ps[h]) + base[h]);
            }
#pragma unroll
            for (int off = 32; off; off >>= 1) p += __shfl_xor(p, off);
            if (lane == 0) sc[t] = p;
        }
        __syncthreads();
        if (wv == 0) {                      // softmax over 64 t
            float s = sc[lane], mx = s;
#pragma unroll
            for (int off = 32; off; off >>= 1) mx = fmaxf(mx, __shfl_xor(mx, off));
            float e = __expf(s - mx), sum = e;
#pragma unroll
            for (int off = 32; off; off >>= 1) sum += __shfl_xor(sum, off);
            sc[lane] = e / sum;
        }
        __syncthreads();

        // ---- a partials: red[kh][h] = sum over t-half of alpha*h_s ----
        {
            const float* hp = h_s + (size_t)b * 512 + j;
            float p = 0.0f;
#pragma unroll
            for (int t4 = 0; t4 < 8; ++t4) {
                int t = kh * 32 + t4 * 4;
                float4 s4 = *(const float4*)&sc[t];
                p += s4.x * ntload(&hp[(size_t)(t + 0) * 65536])
                   + s4.y * ntload(&hp[(size_t)(t + 1) * 65536])
                   + s4.z * ntload(&hp[(size_t)(t + 2) * 65536])
                   + s4.w * ntload(&hp[(size_t)(t + 3) * 65536]);
            }
            red[kh * 512 + j] = p;
        }
        __syncthreads();
        if (tid < 512) av[tid] = red[tid] + red[512 + tid];
        __syncthreads();

        // ---- gates partials (pipelined per gate): red3[g][kh][j] ----
        {
            float pg[3];
#pragma unroll
            for (int g = 0; g < 3; ++g) {
                const uint4* wg = wp3 + g * 512;
                uint4 uA[8], uB[8];
                ldc8(uA, wg, hq0 +  0, 1536);
                ldc8(uB, wg, hq0 +  8, 1536);
                float p = dotc8(uA, &av[(hq0 + 0) * 8]);
                ldc8(uA, wg, hq0 + 16, 1536);
                p += dotc8(uB, &av[(hq0 +  8) * 8]);
                ldc8(uB, wg, hq0 + 24, 1536);
                p += dotc8(uA, &av[(hq0 + 16) * 8]);
                p += dotc8(uB, &av[(hq0 + 24) * 8]);
                pg[g] = p;
            }
            red3[(0 * 2 + kh) * 512 + j] = pg[0];
            red3[(1 * 2 + kh) * 512 + j] = pg[1];
            red3[(2 * 2 + kh) * 512 + j] = pg[2];
        }
        __syncthreads();
        if (tid < 512) {
            const size_t m = (size_t)k * 128 + b;
            float gi = red3[tid]        + red3[512 + tid]
                     + ntload(&pre_m_h[(m * 3 + 0) * 512 + tid]);
            float gg = red3[1024 + tid] + red3[1536 + tid]
                     + ntload(&pre_m_h[(m * 3 + 1) * 512 + tid]);
            float go = red3[2048 + tid] + red3[2560 + tid]
                     + ntload(&pre_m_h[(m * 3 + 2) * 512 + tid]);
            float cc = fast_sigmoid(gi) * fast_tanh(gg);
            hm[tid]  = fast_sigmoid(go) * fast_tanh(cc);
        }
        __syncthreads();
    }

    // ---- FC epilogue: out[b,c] = hm . fc_w[c] + fc_b[c], waves 0..2 ----
    if (wv < 3) {
        float p = 0.0f;
#pragma unroll
        for (int u = 0; u < 8; ++u) {
            int h = lane + 64 * u;
            p += hm[h] * fc_w[wv * 512 + h];
        }
#pragma unroll
        for (int off = 32; off; off >>= 1) p += __shfl_xor(p, off);
        if (lane == 0) out[b * 3 + wv] = p + fc_b[wv];
    }
}

extern "C" void kernel_launch(void* const* d_in, const int* in_sizes, int n_in,
                              void* d_out, int out_size, void* d_ws, size_t ws_size,
                              hipStream_t stream)
{
    (void)in_sizes; (void)n_in; (void)out_size;
    const int*   premise    = (const int*)d_in[0];
    const int*   hypothesis = (const int*)d_in[2];
    const float* embed  = (const float*)d_in[4];
    const float* w_e    = (const float*)d_in[5];
    const float* Ws     = (const float*)d_in[6];
    const float* Wt     = (const float*)d_in[7];
    const float* Wm     = (const float*)d_in[8];
    const float* Wih_p  = (const float*)d_in[9];
    const float* bih_p  = (const float*)d_in[10];
    const float* bhh_p  = (const float*)d_in[11];
    const float* Wih_h  = (const float*)d_in[12];
    const float* bih_h  = (const float*)d_in[13];
    const float* bhh_h  = (const float*)d_in[14];
    const float* Wih_m  = (const float*)d_in[15];
    const float* bih_m  = (const float*)d_in[16];
    const float* bhh_m  = (const float*)d_in[17];
    const float* fc_w   = (const float*)d_in[18];
    const float* fc_b   = (const float*)d_in[19];

    float* ws      = (float*)d_ws;
    float* h_s     = ws;                      // 8192*512
    float* h_t     = h_s    + 4194304;        // 8192*512 (reused below)
    float* pre_s   = h_t    + 4194304;
    float* pre_t   = pre_s  + 4194304;
    float* pre_m_h = pre_t  + 4194304;        // 8192*3*512
    // bf16-packed transposed weights alias h_t's buffer: transposes are
    // launched AFTER the last gemm that reads h_t (stream-ordered).
    unsigned* WmT2 = (unsigned*)h_t;          // 256*512 dwords  (0.5 MB)
    unsigned* W3t2 = WmT2 + 131072;           // 256*1536 dwords (1.5 MB)
    float* outp    = (float*)d_out;
    if (ws_size < (size_t)29556736 * 4) return;

    dim3 blk(256);

    // Phase A (parallel)
    gemm3_kernel<64, 3, 0, 1><<<dim3(128, 16), blk, 0, stream>>>(
        embed, premise, 300, Wih_p, 300, 300, bih_p, bhh_p, nullptr, h_s);
    gemm3_kernel<64, 3, 0, 1><<<dim3(128, 16), blk, 0, stream>>>(
        embed, hypothesis, 300, Wih_h, 300, 300, bih_h, bhh_h, nullptr, h_t);
    gemm3_kernel<64, 1, 3, 0><<<dim3(128, 16), blk, 0, stream>>>(
        h_s, nullptr, 512, Ws, 512, 512, nullptr, nullptr, nullptr, pre_s);
    gemm3_kernel<64, 1, 3, 0><<<dim3(128, 16), blk, 0, stream>>>(
        h_t, nullptr, 512, Wt, 512, 512, nullptr, nullptr, nullptr, pre_t);
    gemm3_kernel<64, 3, 1, 0><<<dim3(128, 16), blk, 0, stream>>>(
        h_t, nullptr, 512, Wih_m + 512, 1024, 512, bih_m, bhh_m, nullptr, pre_m_h);

    // Weight transposes (after h_t's last reader; outputs alias h_t space)
    trans_pack_kernel<<<dim3(8, 4, 1), blk, 0, stream>>>(Wm, 512, 0, WmT2, 512);
    trans_pack_kernel<<<dim3(8, 4, 3), blk, 0, stream>>>(Wih_m, 1024, 1, W3t2, 1536);

    // Phase B: 128 independent blocks (one per batch element), no grid sync
    phaseB_kernel<<<dim3(128), dim3(1024), 0, stream>>>(
        pre_s, pre_t, h_s, pre_m_h, WmT2, W3t2, w_e, fc_w, fc_b, outp);
}

// Round 13
// 18035.446 us; speedup vs baseline: 1.4234x; 1.4234x over previous
//
#include <hip/hip_runtime.h>

// MatchLSTM forward (Round 13) = Round 12 + __launch_bounds__(1024, 4).
// Round-12 post-mortem: VGPR_Count stayed 64 (same as Round 10) while the
// double-buffer needed ~104 -> compiler allocated for its default occupancy
// target (8 waves/EU = 64 VGPR cap) and spilled the staging arrays
// (WRITE_SIZE 2.1 GB). Fix: declare the occupancy we actually run at —
// (1024, 4 waves/EU) = 1 block/CU -> 128-VGPR cap. Gates g-loop pinned
// unroll-1 so only one gate's ping-pong pair (64 VGPRs) is live at once.
//
// Structure: phase B independent per batch element (one block per b, 1024
// threads, K-split GEMVs, LDS reductions, no grid sync). Phase A = 5 fp32
// tiled GEMMs (unchanged).

#define DEV static __device__ __forceinline__

DEV float fast_sigmoid(float x) { return 1.0f / (1.0f + __expf(-x)); }
DEV float fast_tanh(float x)    { return 1.0f - 2.0f / (__expf(2.0f * x) + 1.0f); }

// bf16 pack/unpack (RTNE pack; unpack = shift into fp32 exponent position)
DEV unsigned f2bf(float x) {
    unsigned v = __float_as_uint(x);
    return (v + 0x7FFFu + ((v >> 16) & 1u)) >> 16;
}
DEV float blo(unsigned u) { return __uint_as_float(u << 16); }
DEV float bhi(unsigned u) { return __uint_as_float(u & 0xFFFF0000u); }

DEV float ntload(const float* p) { return __builtin_nontemporal_load(p); }

// ---------------------------------------------------------------------------
// Phase A GEMM (unchanged from Round 1; verified passing).
// ---------------------------------------------------------------------------
template<int BM, int NG, int MODE, int GATHER>
__global__ __launch_bounds__(256) void gemm3_kernel(
    const float* __restrict__ A, const int* __restrict__ gidx, int lda,
    const float* __restrict__ W, int ldw, int K,
    const float* __restrict__ bias1, const float* __restrict__ bias2,
    const float* __restrict__ add3, float* __restrict__ out)
{
    constexpr int BK = 32;
    constexpr int TM = BM / 16;
    constexpr int TJ = 2;
    constexpr int AP = BM + 4;
    constexpr int WP = NG * 32 + 4;
    __shared__ __align__(16) float As[BK][AP];
    __shared__ __align__(16) float Wsh[BK][WP];

    const int tid = threadIdx.x;
    const int ty = tid >> 4;
    const int tx = tid & 15;
    const int m0 = blockIdx.x * BM;
    const int j0 = blockIdx.y * 32;

    float acc[TM][TJ][NG];
#pragma unroll
    for (int im = 0; im < TM; ++im)
#pragma unroll
        for (int ij = 0; ij < TJ; ++ij)
#pragma unroll
            for (int g = 0; g < NG; ++g) acc[im][ij][g] = 0.0f;

    for (int k0 = 0; k0 < K; k0 += BK) {
#pragma unroll
        for (int i = tid; i < BM * BK; i += 256) {
            int r = i >> 5, c = i & 31;
            int gk = k0 + c;
            float v = 0.0f;
            if (gk < K) {
                int arow = GATHER ? gidx[m0 + r] : (m0 + r);
                v = A[arow * lda + gk];
            }
            As[c][r] = v;
        }
#pragma unroll
        for (int i = tid; i < NG * 32 * BK; i += 256) {
            int rl = i >> 5, c = i & 31;
            int g = rl >> 5, jj = rl & 31;
            int row = (g == 0 ? 0 : (g == 1 ? 1024 : 1536)) + j0 + jj;
            int gk = k0 + c;
            float v = (gk < K) ? W[row * ldw + gk] : 0.0f;
            Wsh[c][rl] = v;
        }
        __syncthreads();
#pragma unroll
        for (int kk = 0; kk < BK; ++kk) {
            float av[TM];
            if constexpr (TM == 4) {
                float4 t4 = *reinterpret_cast<const float4*>(&As[kk][ty * 4]);
                av[0] = t4.x; av[1] = t4.y; av[2] = t4.z; av[3] = t4.w;
            } else {
                float2 t2 = *reinterpret_cast<const float2*>(&As[kk][ty * 2]);
                av[0] = t2.x; av[1] = t2.y;
            }
#pragma unroll
            for (int g = 0; g < NG; ++g) {
                float2 w2 = *reinterpret_cast<const float2*>(&Wsh[kk][g * 32 + tx * 2]);
#pragma unroll
                for (int im = 0; im < TM; ++im) {
                    acc[im][0][g] += av[im] * w2.x;
                    acc[im][1][g] += av[im] * w2.y;
                }
            }
        }
        __syncthreads();
    }

#pragma unroll
    for (int im = 0; im < TM; ++im) {
        int m = m0 + ty * TM + im;
#pragma unroll
        for (int ij = 0; ij < TJ; ++ij) {
            int j = j0 + tx * TJ + ij;
            if constexpr (MODE == 3) {
                out[m * 512 + j] = acc[im][ij][0];
            } else if constexpr (MODE == 1) {
                out[(m * 3 + 0) * 512 + j] = acc[im][ij][0] + bias1[j] + bias2[j];
                out[(m * 3 + 1) * 512 + j] = acc[im][ij][1] + bias1[1024 + j] + bias2[1024 + j];
                out[(m * 3 + 2) * 512 + j] = acc[im][ij][2] + bias1[1536 + j] + bias2[1536 + j];
            } else if constexpr (MODE == 0) {
                float gi = acc[im][ij][0] + bias1[j] + bias2[j];
                float gg = acc[im][ij][1] + bias1[1024 + j] + bias2[1024 + j];
                float go = acc[im][ij][2] + bias1[1536 + j] + bias2[1536 + j];
                float c  = fast_sigmoid(gi) * fast_tanh(gg);
                out[m * 512 + j] = fast_sigmoid(go) * fast_tanh(c);
            } else {
                float gi = acc[im][ij][0] + add3[(m * 3 + 0) * 512 + j];
                float gg = acc[im][ij][1] + add3[(m * 3 + 1) * 512 + j];
                float go = acc[im][ij][2] + add3[(m * 3 + 2) * 512 + j];
                float c  = fast_sigmoid(gi) * fast_tanh(gg);
                out[m * 512 + j] = fast_sigmoid(go) * fast_tanh(c);
            }
        }
    }
}

// ---------------------------------------------------------------------------
// Transpose + bf16-pack into uint4 layout (verified, absmax 9.8e-4):
//   uint4 Wpk[h/8][cols]; [hq][col] packs W[col][8hq..8hq+7] as 4 bf16-pair
//   dwords. dword index for pair q=(h/2), col: (q>>2)*(4*out_ld)+4*col+(q&3).
// ---------------------------------------------------------------------------
__global__ __launch_bounds__(256) void trans_pack_kernel(
    const float* __restrict__ W, int ld, int gates,
    unsigned* __restrict__ out, int out_ld)
{
    __shared__ float tile[64][129];
    const int j0 = blockIdx.x * 64;
    const int h0 = blockIdx.y * 128;
    const int g  = blockIdx.z;
    const int row_base = gates ? (g == 0 ? 0 : (g == 1 ? 1024 : 1536)) : 0;
    const int out_col  = gates ? g * 512 : 0;

    for (int i = threadIdx.x; i < 64 * 128; i += 256) {
        int jj = i >> 7, hh = i & 127;
        tile[jj][hh] = W[(size_t)(row_base + j0 + jj) * ld + h0 + hh];
    }
    __syncthreads();
    for (int i = threadIdx.x; i < 4096; i += 256) {
        int jj = i & 63, q = i >> 6;
        int gq = h0 / 2 + q;
        unsigned lo = f2bf(tile[jj][2 * q]);
        unsigned hi = f2bf(tile[jj][2 * q + 1]);
        int col = out_col + j0 + jj;
        out[(size_t)(gq >> 2) * (4 * out_ld) + 4 * col + (gq & 3)] = lo | (hi << 16);
    }
}

// ---- software-pipeline building blocks -----------------------------------
DEV void ldc8(uint4* u, const uint4* wp, int row0, int stride_u4)
{
#pragma unroll
    for (int z = 0; z < 8; ++z) u[z] = wp[(size_t)(row0 + z) * stride_u4];
}

DEV float dotc8(const uint4* u, const float* v)
{
    float p = 0.0f;
#pragma unroll
    for (int z = 0; z < 8; ++z) {
        float4 vA = *(const float4*)&v[z * 8];
        float4 vB = *(const float4*)&v[z * 8 + 4];
        p += blo(u[z].x) * vA.x + bhi(u[z].x) * vA.y
           + blo(u[z].y) * vA.z + bhi(u[z].y) * vA.w
           + blo(u[z].z) * vB.x + bhi(u[z].z) * vB.y
           + blo(u[z].w) * vB.z + bhi(u[z].w) * vB.w;
    }
    return p;
}

// ---------------------------------------------------------------------------
// Phase B: one block per batch element b, 1024 threads, 64 steps, no grid
// sync. Thread = (kh = tid>>9, j = tid&511); every GEMV K-split across the
// two halves with an LDS partial reduction. Weight GEMVs double-buffered:
// load chunk c+1 while computing chunk c (8+8 uint4 in flight).
// __launch_bounds__(1024, 4): 4 waves/EU = the 1 block/CU we actually run
// -> 128-VGPR cap (R12's default gave 64 and spilled 2.1 GB).
// ---------------------------------------------------------------------------
__global__ __launch_bounds__(1024, 4) void phaseB_kernel(
    const float* __restrict__ pre_s, const float* __restrict__ pre_t,
    const float* __restrict__ h_s,   const float* __restrict__ pre_m_h,
    const unsigned* __restrict__ WmT2, const unsigned* __restrict__ W3t2,
    const float* __restrict__ w_e,
    const float* __restrict__ fc_w,  const float* __restrict__ fc_b,
    float* __restrict__ out)
{
    __shared__ __align__(16) float hm[512];
    __shared__ __align__(16) float av[512];
    __shared__ __align__(16) float base[512];
    __shared__ __align__(16) float wesh[512];
    __shared__ __align__(16) float sc[64];
    __shared__ __align__(16) float red[2 * 512];       //  4 KB
    __shared__ __align__(16) float red3[3 * 2 * 512];  // 12 KB

    const int b    = blockIdx.x;
    const int tid  = threadIdx.x;          // 0..1023
    const int wv   = tid >> 6;             // 0..15
    const int lane = tid & 63;
    const int j    = tid & 511;            // output column
    const int kh   = tid >> 9;             // K-half (0/1)
    const int hq0  = kh * 32;              // this half's packed-row base

    if (tid < 512) { wesh[tid] = w_e[tid]; hm[tid] = 0.0f; }
    __syncthreads();

    const uint4* wpm = (const uint4*)WmT2 + j;   // [64][512]  uint4 view
    const uint4* wp3 = (const uint4*)W3t2 + j;   // [64][1536] uint4 view

    for (int k = 0; k < 64; ++k) {
        // ---- wm partials (pipelined): red[kh][j] = hm[khalf].Wm[j][khalf]
        if (k > 0) {
            uint4 uA[8], uB[8];
            ldc8(uA, wpm, hq0 +  0, 512);
            ldc8(uB, wpm, hq0 +  8, 512);
            float p = dotc8(uA, &hm[(hq0 + 0) * 8]);
            ldc8(uA, wpm, hq0 + 16, 512);
            p += dotc8(uB, &hm[(hq0 +  8) * 8]);
            ldc8(uB, wpm, hq0 + 24, 512);
            p += dotc8(uA, &hm[(hq0 + 16) * 8]);
            p += dotc8(uB, &hm[(hq0 + 24) * 8]);
            red[kh * 512 + j] = p;
        }
        __syncthreads();
        if (tid < 512) {
            float wmj = (k > 0) ? (red[tid] + red[512 + tid]) : 0.0f;
            base[tid] = ntload(&pre_t[((size_t)k * 128 + b) * 512 + tid]) + wmj;
        }
        __syncthreads();

        // ---- scores: wave wv handles t = wv*4 .. wv*4+3 ----
#pragma unroll
        for (int tt = 0; tt < 4; ++tt) {
            int t = wv * 4 + tt;
            const float* ps = pre_s + ((size_t)t * 128 + b) * 512;
            float p = 0.0f;
#pragma unroll
            for (int u = 0; u < 8; ++u) {
                int h = lane + 64 * u;
                p += wesh[h] * fast_tanh(ntload(&ps[h]) + base[h]);
            }
#pragma unroll
            for (int off = 32; off; off >>= 1) p += __shfl_xor(p, off);
            if (lane == 0) sc[t] = p;
        }
        __syncthreads();
        if (wv == 0) {                      // softmax over 64 t
            float s = sc[lane], mx = s;
#pragma unroll
            for (int off = 32; off; off >>= 1) mx = fmaxf(mx, __shfl_xor(mx, off));
            float e = __expf(s - mx), sum = e;
#pragma unroll
            for (int off = 32; off; off >>= 1) sum += __shfl_xor(sum, off);
            sc[lane] = e / sum;
        }
        __syncthreads();

        // ---- a partials: red[kh][h] = sum over t-half of alpha*h_s ----
        {
            const float* hp = h_s + (size_t)b * 512 + j;
            float p = 0.0f;
#pragma unroll
            for (int t4 = 0; t4 < 8; ++t4) {
                int t = kh * 32 + t4 * 4;
                float4 s4 = *(const float4*)&sc[t];
                p += s4.x * ntload(&hp[(size_t)(t + 0) * 65536])
                   + s4.y * ntload(&hp[(size_t)(t + 1) * 65536])
                   + s4.z * ntload(&hp[(size_t)(t + 2) * 65536])
                   + s4.w * ntload(&hp[(size_t)(t + 3) * 65536]);
            }
            red[kh * 512 + j] = p;
        }
        __syncthreads();
        if (tid < 512) av[tid] = red[tid] + red[512 + tid];
        __syncthreads();

        // ---- gates partials (pipelined per gate, ONE gate live at a time)
        {
            float pg[3];
#pragma unroll 1
            for (int g = 0; g < 3; ++g) {
                const uint4* wg = wp3 + g * 512;
                uint4 uA[8], uB[8];
                ldc8(uA, wg, hq0 +  0, 1536);
                ldc8(uB, wg, hq0 +  8, 1536);
                float p = dotc8(uA, &av[(hq0 + 0) * 8]);
                ldc8(uA, wg, hq0 + 16, 1536);
                p += dotc8(uB, &av[(hq0 +  8) * 8]);
                ldc8(uB, wg, hq0 + 24, 1536);
                p += dotc8(uA, &av[(hq0 + 16) * 8]);
                p += dotc8(uB, &av[(hq0 + 24) * 8]);
                pg[g] = p;
            }
            red3[(0 * 2 + kh) * 512 + j] = pg[0];
            red3[(1 * 2 + kh) * 512 + j] = pg[1];
            red3[(2 * 2 + kh) * 512 + j] = pg[2];
        }
        __syncthreads();
        if (tid < 512) {
            const size_t m = (size_t)k * 128 + b;
            float gi = red3[tid]        + red3[512 + tid]
                     + ntload(&pre_m_h[(m * 3 + 0) * 512 + tid]);
            float gg = red3[1024 + tid] + red3[1536 + tid]
                     + ntload(&pre_m_h[(m * 3 + 1) * 512 + tid]);
            float go = red3[2048 + tid] + red3[2560 + tid]
                     + ntload(&pre_m_h[(m * 3 + 2) * 512 + tid]);
            float cc = fast_sigmoid(gi) * fast_tanh(gg);
            hm[tid]  = fast_sigmoid(go) * fast_tanh(cc);
        }
        __syncthreads();
    }

    // ---- FC epilogue: out[b,c] = hm . fc_w[c] + fc_b[c], waves 0..2 ----
    if (wv < 3) {
        float p = 0.0f;
#pragma unroll
        for (int u = 0; u < 8; ++u) {
            int h = lane + 64 * u;
            p += hm[h] * fc_w[wv * 512 + h];
        }
#pragma unroll
        for (int off = 32; off; off >>= 1) p += __shfl_xor(p, off);
        if (lane == 0) out[b * 3 + wv] = p + fc_b[wv];
    }
}

extern "C" void kernel_launch(void* const* d_in, const int* in_sizes, int n_in,
                              void* d_out, int out_size, void* d_ws, size_t ws_size,
                              hipStream_t stream)
{
    (void)in_sizes; (void)n_in; (void)out_size;
    const int*   premise    = (const int*)d_in[0];
    const int*   hypothesis = (const int*)d_in[2];
    const float* embed  = (const float*)d_in[4];
    const float* w_e    = (const float*)d_in[5];
    const float* Ws     = (const float*)d_in[6];
    const float* Wt     = (const float*)d_in[7];
    const float* Wm     = (const float*)d_in[8];
    const float* Wih_p  = (const float*)d_in[9];
    const float* bih_p  = (const float*)d_in[10];
    const float* bhh_p  = (const float*)d_in[11];
    const float* Wih_h  = (const float*)d_in[12];
    const float* bih_h  = (const float*)d_in[13];
    const float* bhh_h  = (const float*)d_in[14];
    const float* Wih_m  = (const float*)d_in[15];
    const float* bih_m  = (const float*)d_in[16];
    const float* bhh_m  = (const float*)d_in[17];
    const float* fc_w   = (const float*)d_in[18];
    const float* fc_b   = (const float*)d_in[19];

    float* ws      = (float*)d_ws;
    float* h_s     = ws;                      // 8192*512
    float* h_t     = h_s    + 4194304;        // 8192*512 (reused below)
    float* pre_s   = h_t    + 4194304;
    float* pre_t   = pre_s  + 4194304;
    float* pre_m_h = pre_t  + 4194304;        // 8192*3*512
    // bf16-packed transposed weights alias h_t's buffer: transposes are
    // launched AFTER the last gemm that reads h_t (stream-ordered).
    unsigned* WmT2 = (unsigned*)h_t;          // 256*512 dwords  (0.5 MB)
    unsigned* W3t2 = WmT2 + 131072;           // 256*1536 dwords (1.5 MB)
    float* outp    = (float*)d_out;
    if (ws_size < (size_t)29556736 * 4) return;

    dim3 blk(256);

    // Phase A (parallel)
    gemm3_kernel<64, 3, 0, 1><<<dim3(128, 16), blk, 0, stream>>>(
        embed, premise, 300, Wih_p, 300, 300, bih_p, bhh_p, nullptr, h_s);
    gemm3_kernel<64, 3, 0, 1><<<dim3(128, 16), blk, 0, stream>>>(
        embed, hypothesis, 300, Wih_h, 300, 300, bih_h, bhh_h, nullptr, h_t);
    gemm3_kernel<64, 1, 3, 0><<<dim3(128, 16), blk, 0, stream>>>(
        h_s, nullptr, 512, Ws, 512, 512, nullptr, nullptr, nullptr, pre_s);
    gemm3_kernel<64, 1, 3, 0><<<dim3(128, 16), blk, 0, stream>>>(
        h_t, nullptr, 512, Wt, 512, 512, nullptr, nullptr, nullptr, pre_t);
    gemm3_kernel<64, 3, 1, 0><<<dim3(128, 16), blk, 0, stream>>>(
        h_t, nullptr, 512, Wih_m + 512, 1024, 512, bih_m, bhh_m, nullptr, pre_m_h);

    // Weight transposes (after h_t's last reader; outputs alias h_t space)
    trans_pack_kernel<<<dim3(8, 4, 1), blk, 0, stream>>>(Wm, 512, 0, WmT2, 512);
    trans_pack_kernel<<<dim3(8, 4, 3), blk, 0, stream>>>(Wih_m, 1024, 1, W3t2, 1536);

    // Phase B: 128 independent blocks (one per batch element), no grid sync
    phaseB_kernel<<<dim3(128), dim3(1024), 0, stream>>>(
        pre_s, pre_t, h_s, pre_m_h, WmT2, W3t2, w_e, fc_w, fc_b, outp);
}

// Round 14
// 2697.958 us; speedup vs baseline: 9.5149x; 6.6849x over previous
//
#include <hip/hip_runtime.h>

// MatchLSTM forward (Round 14).
// phaseB: REVERTED verbatim to Round 10 (1932 us, VGPR 64, no spills).
//   Lesson R12/R13: 1024-thread kernels get 64 VGPRs from this compiler no
//   matter what launch_bounds says -> double-buffered staging always spills.
// Phase A: pre_s/pre_t GEMMs (MODE-3 fp32, ~170us each) replaced by a
//   bf16x3-split MFMA kernel (hi/lo decomposition, 3 mfma/K-step, lo*lo
//   dropped -> ~2^-16 rel error). Layouts per HW-verified guide facts:
//   A[m=lane&15][k=quad*8+j], C/D col=lane&15 row=quad*4+reg; W[n][k]
//   row-major is exactly the B-fragment gather (B[k][n], n=lane&15).

#define DEV static __device__ __forceinline__

DEV float fast_sigmoid(float x) { return 1.0f / (1.0f + __expf(-x)); }
DEV float fast_tanh(float x)    { return 1.0f - 2.0f / (__expf(2.0f * x) + 1.0f); }

DEV unsigned f2bf(float x) {
    unsigned v = __float_as_uint(x);
    return (v + 0x7FFFu + ((v >> 16) & 1u)) >> 16;
}
DEV float blo(unsigned u) { return __uint_as_float(u << 16); }
DEV float bhi(unsigned u) { return __uint_as_float(u & 0xFFFF0000u); }

DEV float ntload(const float* p) { return __builtin_nontemporal_load(p); }

typedef __attribute__((ext_vector_type(8))) short bfrag;   // 8 bf16
typedef __attribute__((ext_vector_type(4))) float ffrag;   // 4 fp32 acc

// ---------------------------------------------------------------------------
// Phase A GEMM (fp32; used for the two encoders + pre_m_h).
// ---------------------------------------------------------------------------
template<int BM, int NG, int MODE, int GATHER>
__global__ __launch_bounds__(256) void gemm3_kernel(
    const float* __restrict__ A, const int* __restrict__ gidx, int lda,
    const float* __restrict__ W, int ldw, int K,
    const float* __restrict__ bias1, const float* __restrict__ bias2,
    const float* __restrict__ add3, float* __restrict__ out)
{
    constexpr int BK = 32;
    constexpr int TM = BM / 16;
    constexpr int TJ = 2;
    constexpr int AP = BM + 4;
    constexpr int WP = NG * 32 + 4;
    __shared__ __align__(16) float As[BK][AP];
    __shared__ __align__(16) float Wsh[BK][WP];

    const int tid = threadIdx.x;
    const int ty = tid >> 4;
    const int tx = tid & 15;
    const int m0 = blockIdx.x * BM;
    const int j0 = blockIdx.y * 32;

    float acc[TM][TJ][NG];
#pragma unroll
    for (int im = 0; im < TM; ++im)
#pragma unroll
        for (int ij = 0; ij < TJ; ++ij)
#pragma unroll
            for (int g = 0; g < NG; ++g) acc[im][ij][g] = 0.0f;

    for (int k0 = 0; k0 < K; k0 += BK) {
#pragma unroll
        for (int i = tid; i < BM * BK; i += 256) {
            int r = i >> 5, c = i & 31;
            int gk = k0 + c;
            float v = 0.0f;
            if (gk < K) {
                int arow = GATHER ? gidx[m0 + r] : (m0 + r);
                v = A[arow * lda + gk];
            }
            As[c][r] = v;
        }
#pragma unroll
        for (int i = tid; i < NG * 32 * BK; i += 256) {
            int rl = i >> 5, c = i & 31;
            int g = rl >> 5, jj = rl & 31;
            int row = (g == 0 ? 0 : (g == 1 ? 1024 : 1536)) + j0 + jj;
            int gk = k0 + c;
            float v = (gk < K) ? W[row * ldw + gk] : 0.0f;
            Wsh[c][rl] = v;
        }
        __syncthreads();
#pragma unroll
        for (int kk = 0; kk < BK; ++kk) {
            float av[TM];
            if constexpr (TM == 4) {
                float4 t4 = *reinterpret_cast<const float4*>(&As[kk][ty * 4]);
                av[0] = t4.x; av[1] = t4.y; av[2] = t4.z; av[3] = t4.w;
            } else {
                float2 t2 = *reinterpret_cast<const float2*>(&As[kk][ty * 2]);
                av[0] = t2.x; av[1] = t2.y;
            }
#pragma unroll
            for (int g = 0; g < NG; ++g) {
                float2 w2 = *reinterpret_cast<const float2*>(&Wsh[kk][g * 32 + tx * 2]);
#pragma unroll
                for (int im = 0; im < TM; ++im) {
                    acc[im][0][g] += av[im] * w2.x;
                    acc[im][1][g] += av[im] * w2.y;
                }
            }
        }
        __syncthreads();
    }

#pragma unroll
    for (int im = 0; im < TM; ++im) {
        int m = m0 + ty * TM + im;
#pragma unroll
        for (int ij = 0; ij < TJ; ++ij) {
            int j = j0 + tx * TJ + ij;
            if constexpr (MODE == 3) {
                out[m * 512 + j] = acc[im][ij][0];
            } else if constexpr (MODE == 1) {
                out[(m * 3 + 0) * 512 + j] = acc[im][ij][0] + bias1[j] + bias2[j];
                out[(m * 3 + 1) * 512 + j] = acc[im][ij][1] + bias1[1024 + j] + bias2[1024 + j];
                out[(m * 3 + 2) * 512 + j] = acc[im][ij][2] + bias1[1536 + j] + bias2[1536 + j];
            } else if constexpr (MODE == 0) {
                float gi = acc[im][ij][0] + bias1[j] + bias2[j];
                float gg = acc[im][ij][1] + bias1[1024 + j] + bias2[1024 + j];
                float go = acc[im][ij][2] + bias1[1536 + j] + bias2[1536 + j];
                float c  = fast_sigmoid(gi) * fast_tanh(gg);
                out[m * 512 + j] = fast_sigmoid(go) * fast_tanh(c);
            } else {
                float gi = acc[im][ij][0] + add3[(m * 3 + 0) * 512 + j];
                float gg = acc[im][ij][1] + add3[(m * 3 + 1) * 512 + j];
                float go = acc[im][ij][2] + add3[(m * 3 + 2) * 512 + j];
                float c  = fast_sigmoid(gi) * fast_tanh(gg);
                out[m * 512 + j] = fast_sigmoid(go) * fast_tanh(c);
            }
        }
    }
}

// ---------------------------------------------------------------------------
// MFMA GEMM: C[M][512] = A[M][512] . W[512][512]^T, fp32 in/out, bf16x3.
// Block 256 thr / 4 waves; WG tile 64M x 64N; wave = 16M x 64N (4 n-frags).
// Per K-step(32): convert A-frag + 4 W-frags to hi/lo bf16, 3 MFMAs each.
// ---------------------------------------------------------------------------
__global__ __launch_bounds__(256) void mfma_nt_kernel(
    const float* __restrict__ A, const float* __restrict__ W,
    float* __restrict__ C)
{
    const int wv   = threadIdx.x >> 6;
    const int lane = threadIdx.x & 63;
    const int row  = lane & 15;
    const int quad = lane >> 4;
    const int m0 = blockIdx.x * 64 + wv * 16;
    const int n0 = blockIdx.y * 64;

    ffrag acc[4];
#pragma unroll
    for (int n = 0; n < 4; ++n)
#pragma unroll
        for (int r = 0; r < 4; ++r) acc[n][r] = 0.0f;

    for (int k0 = 0; k0 < 512; k0 += 32) {
        // A fragment: A[m0+row][k0+quad*8 .. +7]
        const float* ap = A + (size_t)(m0 + row) * 512 + k0 + quad * 8;
        float4 aA = *(const float4*)ap;
        float4 aB = *(const float4*)(ap + 4);
        float av[8] = {aA.x, aA.y, aA.z, aA.w, aB.x, aB.y, aB.z, aB.w};
        bfrag ahi, alo;
#pragma unroll
        for (int z = 0; z < 8; ++z) {
            unsigned h = f2bf(av[z]);
            ahi[z] = (short)h;
            alo[z] = (short)f2bf(av[z] - __uint_as_float(h << 16));
        }
#pragma unroll
        for (int n = 0; n < 4; ++n) {
            const float* wp = W + (size_t)(n0 + n * 16 + row) * 512 + k0 + quad * 8;
            float4 wA = *(const float4*)wp;
            float4 wB = *(const float4*)(wp + 4);
            float wvv[8] = {wA.x, wA.y, wA.z, wA.w, wB.x, wB.y, wB.z, wB.w};
            bfrag whi, wlo;
#pragma unroll
            for (int z = 0; z < 8; ++z) {
                unsigned h = f2bf(wvv[z]);
                whi[z] = (short)h;
                wlo[z] = (short)f2bf(wvv[z] - __uint_as_float(h << 16));
            }
            acc[n] = __builtin_amdgcn_mfma_f32_16x16x32_bf16(ahi, whi, acc[n], 0, 0, 0);
            acc[n] = __builtin_amdgcn_mfma_f32_16x16x32_bf16(alo, whi, acc[n], 0, 0, 0);
            acc[n] = __builtin_amdgcn_mfma_f32_16x16x32_bf16(ahi, wlo, acc[n], 0, 0, 0);
        }
    }
    // C/D layout: col = lane&15, row = quad*4 + reg
#pragma unroll
    for (int n = 0; n < 4; ++n)
#pragma unroll
        for (int r = 0; r < 4; ++r)
            C[(size_t)(m0 + quad * 4 + r) * 512 + n0 + n * 16 + row] = acc[n][r];
}

// ---------------------------------------------------------------------------
// Transpose + bf16-pack into uint4 layout (verified, absmax 9.8e-4).
// ---------------------------------------------------------------------------
__global__ __launch_bounds__(256) void trans_pack_kernel(
    const float* __restrict__ W, int ld, int gates,
    unsigned* __restrict__ out, int out_ld)
{
    __shared__ float tile[64][129];
    const int j0 = blockIdx.x * 64;
    const int h0 = blockIdx.y * 128;
    const int g  = blockIdx.z;
    const int row_base = gates ? (g == 0 ? 0 : (g == 1 ? 1024 : 1536)) : 0;
    const int out_col  = gates ? g * 512 : 0;

    for (int i = threadIdx.x; i < 64 * 128; i += 256) {
        int jj = i >> 7, hh = i & 127;
        tile[jj][hh] = W[(size_t)(row_base + j0 + jj) * ld + h0 + hh];
    }
    __syncthreads();
    for (int i = threadIdx.x; i < 4096; i += 256) {
        int jj = i & 63, q = i >> 6;
        int gq = h0 / 2 + q;
        unsigned lo = f2bf(tile[jj][2 * q]);
        unsigned hi = f2bf(tile[jj][2 * q + 1]);
        int col = out_col + j0 + jj;
        out[(size_t)(gq >> 2) * (4 * out_ld) + 4 * col + (gq & 3)] = lo | (hi << 16);
    }
}

// ---------------------------------------------------------------------------
// Phase B: Round-10 kernel VERBATIM (verified 1932 us, VGPR 64, no spills).
// One block per batch element b, 1024 threads, K-split GEMVs, LDS
// reductions, no grid sync, single-buffered 8x uint4 staging.
// ---------------------------------------------------------------------------
__global__ __launch_bounds__(1024) void phaseB_kernel(
    const float* __restrict__ pre_s, const float* __restrict__ pre_t,
    const float* __restrict__ h_s,   const float* __restrict__ pre_m_h,
    const unsigned* __restrict__ WmT2, const unsigned* __restrict__ W3t2,
    const float* __restrict__ w_e,
    const float* __restrict__ fc_w,  const float* __restrict__ fc_b,
    float* __restrict__ out)
{
    __shared__ __align__(16) float hm[512];
    __shared__ __align__(16) float av[512];
    __shared__ __align__(16) float base[512];
    __shared__ __align__(16) float wesh[512];
    __shared__ __align__(16) float sc[64];
    __shared__ __align__(16) float red[2 * 512];
    __shared__ __align__(16) float red3[3 * 2 * 512];

    const int b    = blockIdx.x;
    const int tid  = threadIdx.x;
    const int wv   = tid >> 6;
    const int lane = tid & 63;
    const int j    = tid & 511;
    const int kh   = tid >> 9;
    const int hq0  = kh * 32;

    if (tid < 512) { wesh[tid] = w_e[tid]; hm[tid] = 0.0f; }
    __syncthreads();

    const uint4* wpm = (const uint4*)WmT2 + j;
    const uint4* wp3 = (const uint4*)W3t2 + j;

    for (int k = 0; k < 64; ++k) {
        if (k > 0) {
            float p = 0.0f;
#pragma unroll 1
            for (int c0 = 0; c0 < 32; c0 += 8) {
                uint4 u[8];
#pragma unroll
                for (int z = 0; z < 8; ++z) u[z] = wpm[(size_t)(hq0 + c0 + z) * 512];
#pragma unroll
                for (int z = 0; z < 8; ++z) {
                    const float* hv = &hm[(hq0 + c0 + z) * 8];
                    float4 vA = *(const float4*)hv;
                    float4 vB = *(const float4*)(hv + 4);
                    p += blo(u[z].x) * vA.x + bhi(u[z].x) * vA.y
                       + blo(u[z].y) * vA.z + bhi(u[z].y) * vA.w
                       + blo(u[z].z) * vB.x + bhi(u[z].z) * vB.y
                       + blo(u[z].w) * vB.z + bhi(u[z].w) * vB.w;
                }
            }
            red[kh * 512 + j] = p;
        }
        __syncthreads();
        if (tid < 512) {
            float wmj = (k > 0) ? (red[tid] + red[512 + tid]) : 0.0f;
            base[tid] = ntload(&pre_t[((size_t)k * 128 + b) * 512 + tid]) + wmj;
        }
        __syncthreads();

#pragma unroll
        for (int tt = 0; tt < 4; ++tt) {
            int t = wv * 4 + tt;
            const float* ps = pre_s + ((size_t)t * 128 + b) * 512;
            float p = 0.0f;
#pragma unroll
            for (int u = 0; u < 8; ++u) {
                int h = lane + 64 * u;
                p += wesh[h] * fast_tanh(ntload(&ps[h]) + base[h]);
            }
#pragma unroll
            for (int off = 32; off; off >>= 1) p += __shfl_xor(p, off);
            if (lane == 0) sc[t] = p;
        }
        __syncthreads();
        if (wv == 0) {
            float s = sc[lane], mx = s;
#pragma unroll
            for (int off = 32; off; off >>= 1) mx = fmaxf(mx, __shfl_xor(mx, off));
            float e = __expf(s - mx), sum = e;
#pragma unroll
            for (int off = 32; off; off >>= 1) sum += __shfl_xor(sum, off);
            sc[lane] = e / sum;
        }
        __syncthreads();

        {
            const float* hp = h_s + (size_t)b * 512 + j;
            float p = 0.0f;
#pragma unroll
            for (int t4 = 0; t4 < 8; ++t4) {
                int t = kh * 32 + t4 * 4;
                float4 s4 = *(const float4*)&sc[t];
                p += s4.x * ntload(&hp[(size_t)(t + 0) * 65536])
                   + s4.y * ntload(&hp[(size_t)(t + 1) * 65536])
                   + s4.z * ntload(&hp[(size_t)(t + 2) * 65536])
                   + s4.w * ntload(&hp[(size_t)(t + 3) * 65536]);
            }
            red[kh * 512 + j] = p;
        }
        __syncthreads();
        if (tid < 512) av[tid] = red[tid] + red[512 + tid];
        __syncthreads();

#pragma unroll 1
        for (int g = 0; g < 3; ++g) {
            const uint4* wg = wp3 + g * 512;
            float p = 0.0f;
#pragma unroll 1
            for (int c0 = 0; c0 < 32; c0 += 8) {
                uint4 u[8];
#pragma unroll
                for (int z = 0; z < 8; ++z) u[z] = wg[(size_t)(hq0 + c0 + z) * 1536];
#pragma unroll
                for (int z = 0; z < 8; ++z) {
                    const float* vv = &av[(hq0 + c0 + z) * 8];
                    float4 vA = *(const float4*)vv;
                    float4 vB = *(const float4*)(vv + 4);
                    p += blo(u[z].x) * vA.x + bhi(u[z].x) * vA.y
                       + blo(u[z].y) * vA.z + bhi(u[z].y) * vA.w
                       + blo(u[z].z) * vB.x + bhi(u[z].z) * vB.y
                       + blo(u[z].w) * vB.z + bhi(u[z].w) * vB.w;
                }
            }
            red3[(g * 2 + kh) * 512 + j] = p;
        }
        __syncthreads();
        if (tid < 512) {
            const size_t m = (size_t)k * 128 + b;
            float gi = red3[tid]        + red3[512 + tid]
                     + ntload(&pre_m_h[(m * 3 + 0) * 512 + tid]);
            float gg = red3[1024 + tid] + red3[1536 + tid]
                     + ntload(&pre_m_h[(m * 3 + 1) * 512 + tid]);
            float go = red3[2048 + tid] + red3[2560 + tid]
                     + ntload(&pre_m_h[(m * 3 + 2) * 512 + tid]);
            float cc = fast_sigmoid(gi) * fast_tanh(gg);
            hm[tid]  = fast_sigmoid(go) * fast_tanh(cc);
        }
        __syncthreads();
    }

    if (wv < 3) {
        float p = 0.0f;
#pragma unroll
        for (int u = 0; u < 8; ++u) {
            int h = lane + 64 * u;
            p += hm[h] * fc_w[wv * 512 + h];
        }
#pragma unroll
        for (int off = 32; off; off >>= 1) p += __shfl_xor(p, off);
        if (lane == 0) out[b * 3 + wv] = p + fc_b[wv];
    }
}

extern "C" void kernel_launch(void* const* d_in, const int* in_sizes, int n_in,
                              void* d_out, int out_size, void* d_ws, size_t ws_size,
                              hipStream_t stream)
{
    (void)in_sizes; (void)n_in; (void)out_size;
    const int*   premise    = (const int*)d_in[0];
    const int*   hypothesis = (const int*)d_in[2];
    const float* embed  = (const float*)d_in[4];
    const float* w_e    = (const float*)d_in[5];
    const float* Ws     = (const float*)d_in[6];
    const float* Wt     = (const float*)d_in[7];
    const float* Wm     = (const float*)d_in[8];
    const float* Wih_p  = (const float*)d_in[9];
    const float* bih_p  = (const float*)d_in[10];
    const float* bhh_p  = (const float*)d_in[11];
    const float* Wih_h  = (const float*)d_in[12];
    const float* bih_h  = (const float*)d_in[13];
    const float* bhh_h  = (const float*)d_in[14];
    const float* Wih_m  = (const float*)d_in[15];
    const float* bih_m  = (const float*)d_in[16];
    const float* bhh_m  = (const float*)d_in[17];
    const float* fc_w   = (const float*)d_in[18];
    const float* fc_b   = (const float*)d_in[19];

    float* ws      = (float*)d_ws;
    float* h_s     = ws;                      // 8192*512
    float* h_t     = h_s    + 4194304;        // 8192*512 (reused below)
    float* pre_s   = h_t    + 4194304;
    float* pre_t   = pre_s  + 4194304;
    float* pre_m_h = pre_t  + 4194304;        // 8192*3*512
    unsigned* WmT2 = (unsigned*)h_t;          // aliases h_t after last reader
    unsigned* W3t2 = WmT2 + 131072;
    float* outp    = (float*)d_out;
    if (ws_size < (size_t)29556736 * 4) return;

    dim3 blk(256);

    // Phase A
    gemm3_kernel<64, 3, 0, 1><<<dim3(128, 16), blk, 0, stream>>>(
        embed, premise, 300, Wih_p, 300, 300, bih_p, bhh_p, nullptr, h_s);
    gemm3_kernel<64, 3, 0, 1><<<dim3(128, 16), blk, 0, stream>>>(
        embed, hypothesis, 300, Wih_h, 300, 300, bih_h, bhh_h, nullptr, h_t);
    // pre_s / pre_t via bf16x3 MFMA (was fp32 gemm3 MODE 3)
    mfma_nt_kernel<<<dim3(128, 8), blk, 0, stream>>>(h_s, Ws, pre_s);
    mfma_nt_kernel<<<dim3(128, 8), blk, 0, stream>>>(h_t, Wt, pre_t);
    gemm3_kernel<64, 3, 1, 0><<<dim3(128, 16), blk, 0, stream>>>(
        h_t, nullptr, 512, Wih_m + 512, 1024, 512, bih_m, bhh_m, nullptr, pre_m_h);

    // Weight transposes (after h_t's last reader; outputs alias h_t space)
    trans_pack_kernel<<<dim3(8, 4, 1), blk, 0, stream>>>(Wm, 512, 0, WmT2, 512);
    trans_pack_kernel<<<dim3(8, 4, 3), blk, 0, stream>>>(Wih_m, 1024, 1, W3t2, 1536);

    // Phase B (Round-10 verbatim)
    phaseB_kernel<<<dim3(128), dim3(1024), 0, stream>>>(
        pre_s, pre_t, h_s, pre_m_h, WmT2, W3t2, w_e, fc_w, fc_b, outp);
}

// Round 15
// 2508.492 us; speedup vs baseline: 10.2335x; 1.0755x over previous
//
#include <hip/hip_runtime.h>

// MatchLSTM forward (Round 15): ALL phase-A GEMMs now bf16x3 MFMA.
//   R14 validated the pattern (absmax bit-identical, layouts verified).
//   New: mfma_g3_kernel (3-gate GEMM, gather + K=300 tail masking + bias,
//   grid y=24 covers gate row-bases {0,1024,1536}; tile never straddles a
//   gate) + enc_gates elementwise. Encoder preacts reuse pre_m_h as scratch.
// phaseB: Round-10 verbatim (1920 us, VGPR 64, no spills — R12/R13 lesson:
//   1024-thread kernels are pinned at 64 VGPRs; no register double-buffer).

#define DEV static __device__ __forceinline__

DEV float fast_sigmoid(float x) { return 1.0f / (1.0f + __expf(-x)); }
DEV float fast_tanh(float x)    { return 1.0f - 2.0f / (__expf(2.0f * x) + 1.0f); }

DEV unsigned f2bf(float x) {
    unsigned v = __float_as_uint(x);
    return (v + 0x7FFFu + ((v >> 16) & 1u)) >> 16;
}
DEV float blo(unsigned u) { return __uint_as_float(u << 16); }
DEV float bhi(unsigned u) { return __uint_as_float(u & 0xFFFF0000u); }

DEV float ntload(const float* p) { return __builtin_nontemporal_load(p); }

typedef __attribute__((ext_vector_type(8))) short bfrag;   // 8 bf16
typedef __attribute__((ext_vector_type(4))) float ffrag;   // 4 fp32 acc

DEV void cvt_hilo(const float* v, bfrag& hi, bfrag& lo)
{
#pragma unroll
    for (int z = 0; z < 8; ++z) {
        unsigned h = f2bf(v[z]);
        hi[z] = (short)h;
        lo[z] = (short)f2bf(v[z] - __uint_as_float(h << 16));
    }
}

// ---------------------------------------------------------------------------
// MFMA GEMM (validated R14): C[M][512] = A[M][512] . W[512][512]^T, bf16x3.
// Block 256 thr / 4 waves; WG tile 64M x 64N; wave = 16M x 64N.
// ---------------------------------------------------------------------------
__global__ __launch_bounds__(256) void mfma_nt_kernel(
    const float* __restrict__ A, const float* __restrict__ W,
    float* __restrict__ C)
{
    const int wv   = threadIdx.x >> 6;
    const int lane = threadIdx.x & 63;
    const int row  = lane & 15;
    const int quad = lane >> 4;
    const int m0 = blockIdx.x * 64 + wv * 16;
    const int n0 = blockIdx.y * 64;

    ffrag acc[4];
#pragma unroll
    for (int n = 0; n < 4; ++n)
#pragma unroll
        for (int r = 0; r < 4; ++r) acc[n][r] = 0.0f;

    for (int k0 = 0; k0 < 512; k0 += 32) {
        const float* ap = A + (size_t)(m0 + row) * 512 + k0 + quad * 8;
        float4 aA = *(const float4*)ap;
        float4 aB = *(const float4*)(ap + 4);
        float av[8] = {aA.x, aA.y, aA.z, aA.w, aB.x, aB.y, aB.z, aB.w};
        bfrag ahi, alo;
        cvt_hilo(av, ahi, alo);
#pragma unroll
        for (int n = 0; n < 4; ++n) {
            const float* wp = W + (size_t)(n0 + n * 16 + row) * 512 + k0 + quad * 8;
            float4 wA = *(const float4*)wp;
            float4 wB = *(const float4*)(wp + 4);
            float wvv[8] = {wA.x, wA.y, wA.z, wA.w, wB.x, wB.y, wB.z, wB.w};
            bfrag whi, wlo;
            cvt_hilo(wvv, whi, wlo);
            acc[n] = __builtin_amdgcn_mfma_f32_16x16x32_bf16(ahi, whi, acc[n], 0, 0, 0);
            acc[n] = __builtin_amdgcn_mfma_f32_16x16x32_bf16(alo, whi, acc[n], 0, 0, 0);
            acc[n] = __builtin_amdgcn_mfma_f32_16x16x32_bf16(ahi, wlo, acc[n], 0, 0, 0);
        }
    }
#pragma unroll
    for (int n = 0; n < 4; ++n)
#pragma unroll
        for (int r = 0; r < 4; ++r)
            C[(size_t)(m0 + quad * 4 + r) * 512 + n0 + n * 16 + row] = acc[n][r];
}

// ---------------------------------------------------------------------------
// 3-gate MFMA GEMM: P[(m*3+g)*512+j] = A[m,:] . W[grow(g)+j,:] + b1 + b2.
// grid = (M/64, 24): blockIdx.y>>3 = gate (block-uniform), (y&7)*64 = j-tile.
// GATHER: A row through gidx. K-tail (K=300): guarded scalar loads on the
// final K-step only (no OOB read past embed's last row).
// ---------------------------------------------------------------------------
template<int GATHER>
__global__ __launch_bounds__(256) void mfma_g3_kernel(
    const float* __restrict__ A, const int* __restrict__ gidx,
    int lda, int K,
    const float* __restrict__ W, int ldw,
    const float* __restrict__ bias1, const float* __restrict__ bias2,
    float* __restrict__ out)
{
    const int wv   = threadIdx.x >> 6;
    const int lane = threadIdx.x & 63;
    const int row  = lane & 15;
    const int quad = lane >> 4;
    const int m0   = blockIdx.x * 64 + wv * 16;
    const int gate = blockIdx.y >> 3;
    const int gbase = (gate == 0) ? 0 : (gate == 1 ? 1024 : 1536);
    const int j0   = (blockIdx.y & 7) * 64;

    const int arow = GATHER ? gidx[m0 + row] : (m0 + row);

    ffrag acc[4];
#pragma unroll
    for (int n = 0; n < 4; ++n)
#pragma unroll
        for (int r = 0; r < 4; ++r) acc[n][r] = 0.0f;

    for (int k0 = 0; k0 < K; k0 += 32) {
        const bool tail = (k0 + 32 > K);
        float av[8];
        if (!tail) {
            const float* ap = A + (size_t)arow * lda + k0 + quad * 8;
            float4 aA = *(const float4*)ap;
            float4 aB = *(const float4*)(ap + 4);
            av[0]=aA.x; av[1]=aA.y; av[2]=aA.z; av[3]=aA.w;
            av[4]=aB.x; av[5]=aB.y; av[6]=aB.z; av[7]=aB.w;
        } else {
#pragma unroll
            for (int z = 0; z < 8; ++z) {
                int kk = k0 + quad * 8 + z;
                av[z] = (kk < K) ? A[(size_t)arow * lda + kk] : 0.0f;
            }
        }
        bfrag ahi, alo;
        cvt_hilo(av, ahi, alo);
#pragma unroll
        for (int n = 0; n < 4; ++n) {
            const int wrow = gbase + j0 + n * 16 + row;
            float wvv[8];
            if (!tail) {
                const float* wp = W + (size_t)wrow * ldw + k0 + quad * 8;
                float4 wA = *(const float4*)wp;
                float4 wB = *(const float4*)(wp + 4);
                wvv[0]=wA.x; wvv[1]=wA.y; wvv[2]=wA.z; wvv[3]=wA.w;
                wvv[4]=wB.x; wvv[5]=wB.y; wvv[6]=wB.z; wvv[7]=wB.w;
            } else {
#pragma unroll
                for (int z = 0; z < 8; ++z) {
                    int kk = k0 + quad * 8 + z;
                    wvv[z] = (kk < K) ? W[(size_t)wrow * ldw + kk] : 0.0f;
                }
            }
            bfrag whi, wlo;
            cvt_hilo(wvv, whi, wlo);
            acc[n] = __builtin_amdgcn_mfma_f32_16x16x32_bf16(ahi, whi, acc[n], 0, 0, 0);
            acc[n] = __builtin_amdgcn_mfma_f32_16x16x32_bf16(alo, whi, acc[n], 0, 0, 0);
            acc[n] = __builtin_amdgcn_mfma_f32_16x16x32_bf16(ahi, wlo, acc[n], 0, 0, 0);
        }
    }
#pragma unroll
    for (int n = 0; n < 4; ++n) {
        const int j = j0 + n * 16 + row;
        const float bb = bias1[gbase + j] + bias2[gbase + j];
#pragma unroll
        for (int r = 0; r < 4; ++r) {
            const int m = m0 + quad * 4 + r;
            out[((size_t)m * 3 + gate) * 512 + j] = acc[n][r] + bb;
        }
    }
}

// ---------------------------------------------------------------------------
// Encoder gate math: h[m][j] = sig(o)*tanh(sig(i)*tanh(g)), preacts in
// P[(m*3+g)*512+j] (biases already added). 4M elems, float4.
// ---------------------------------------------------------------------------
__global__ __launch_bounds__(256) void enc_gates_kernel(
    const float* __restrict__ P, float* __restrict__ h)
{
    const int i = blockIdx.x * 256 + threadIdx.x;     // 0 .. 1,048,575
    const int m = i >> 7;
    const int j4 = (i & 127) * 4;
    const float* p = P + (size_t)m * 1536 + j4;
    float4 gi = *(const float4*)p;
    float4 gg = *(const float4*)(p + 512);
    float4 go = *(const float4*)(p + 1024);
    float4 r;
    r.x = fast_sigmoid(go.x) * fast_tanh(fast_sigmoid(gi.x) * fast_tanh(gg.x));
    r.y = fast_sigmoid(go.y) * fast_tanh(fast_sigmoid(gi.y) * fast_tanh(gg.y));
    r.z = fast_sigmoid(go.z) * fast_tanh(fast_sigmoid(gi.z) * fast_tanh(gg.z));
    r.w = fast_sigmoid(go.w) * fast_tanh(fast_sigmoid(gi.w) * fast_tanh(gg.w));
    *(float4*)&h[(size_t)m * 512 + j4] = r;
}

// ---------------------------------------------------------------------------
// Transpose + bf16-pack into uint4 layout (verified, absmax 9.8e-4).
// ---------------------------------------------------------------------------
__global__ __launch_bounds__(256) void trans_pack_kernel(
    const float* __restrict__ W, int ld, int gates,
    unsigned* __restrict__ out, int out_ld)
{
    __shared__ float tile[64][129];
    const int j0 = blockIdx.x * 64;
    const int h0 = blockIdx.y * 128;
    const int g  = blockIdx.z;
    const int row_base = gates ? (g == 0 ? 0 : (g == 1 ? 1024 : 1536)) : 0;
    const int out_col  = gates ? g * 512 : 0;

    for (int i = threadIdx.x; i < 64 * 128; i += 256) {
        int jj = i >> 7, hh = i & 127;
        tile[jj][hh] = W[(size_t)(row_base + j0 + jj) * ld + h0 + hh];
    }
    __syncthreads();
    for (int i = threadIdx.x; i < 4096; i += 256) {
        int jj = i & 63, q = i >> 6;
        int gq = h0 / 2 + q;
        unsigned lo = f2bf(tile[jj][2 * q]);
        unsigned hi = f2bf(tile[jj][2 * q + 1]);
        int col = out_col + j0 + jj;
        out[(size_t)(gq >> 2) * (4 * out_ld) + 4 * col + (gq & 3)] = lo | (hi << 16);
    }
}

// ---------------------------------------------------------------------------
// Phase B: Round-10 kernel VERBATIM (1920 us, VGPR 64, no spills).
// ---------------------------------------------------------------------------
__global__ __launch_bounds__(1024) void phaseB_kernel(
    const float* __restrict__ pre_s, const float* __restrict__ pre_t,
    const float* __restrict__ h_s,   const float* __restrict__ pre_m_h,
    const unsigned* __restrict__ WmT2, const unsigned* __restrict__ W3t2,
    const float* __restrict__ w_e,
    const float* __restrict__ fc_w,  const float* __restrict__ fc_b,
    float* __restrict__ out)
{
    __shared__ __align__(16) float hm[512];
    __shared__ __align__(16) float av[512];
    __shared__ __align__(16) float base[512];
    __shared__ __align__(16) float wesh[512];
    __shared__ __align__(16) float sc[64];
    __shared__ __align__(16) float red[2 * 512];
    __shared__ __align__(16) float red3[3 * 2 * 512];

    const int b    = blockIdx.x;
    const int tid  = threadIdx.x;
    const int wv   = tid >> 6;
    const int lane = tid & 63;
    const int j    = tid & 511;
    const int kh   = tid >> 9;
    const int hq0  = kh * 32;

    if (tid < 512) { wesh[tid] = w_e[tid]; hm[tid] = 0.0f; }
    __syncthreads();

    const uint4* wpm = (const uint4*)WmT2 + j;
    const uint4* wp3 = (const uint4*)W3t2 + j;

    for (int k = 0; k < 64; ++k) {
        if (k > 0) {
            float p = 0.0f;
#pragma unroll 1
            for (int c0 = 0; c0 < 32; c0 += 8) {
                uint4 u[8];
#pragma unroll
                for (int z = 0; z < 8; ++z) u[z] = wpm[(size_t)(hq0 + c0 + z) * 512];
#pragma unroll
                for (int z = 0; z < 8; ++z) {
                    const float* hv = &hm[(hq0 + c0 + z) * 8];
                    float4 vA = *(const float4*)hv;
                    float4 vB = *(const float4*)(hv + 4);
                    p += blo(u[z].x) * vA.x + bhi(u[z].x) * vA.y
                       + blo(u[z].y) * vA.z + bhi(u[z].y) * vA.w
                       + blo(u[z].z) * vB.x + bhi(u[z].z) * vB.y
                       + blo(u[z].w) * vB.z + bhi(u[z].w) * vB.w;
                }
            }
            red[kh * 512 + j] = p;
        }
        __syncthreads();
        if (tid < 512) {
            float wmj = (k > 0) ? (red[tid] + red[512 + tid]) : 0.0f;
            base[tid] = ntload(&pre_t[((size_t)k * 128 + b) * 512 + tid]) + wmj;
        }
        __syncthreads();

#pragma unroll
        for (int tt = 0; tt < 4; ++tt) {
            int t = wv * 4 + tt;
            const float* ps = pre_s + ((size_t)t * 128 + b) * 512;
            float p = 0.0f;
#pragma unroll
            for (int u = 0; u < 8; ++u) {
                int h = lane + 64 * u;
                p += wesh[h] * fast_tanh(ntload(&ps[h]) + base[h]);
            }
#pragma unroll
            for (int off = 32; off; off >>= 1) p += __shfl_xor(p, off);
            if (lane == 0) sc[t] = p;
        }
        __syncthreads();
        if (wv == 0) {
            float s = sc[lane], mx = s;
#pragma unroll
            for (int off = 32; off; off >>= 1) mx = fmaxf(mx, __shfl_xor(mx, off));
            float e = __expf(s - mx), sum = e;
#pragma unroll
            for (int off = 32; off; off >>= 1) sum += __shfl_xor(sum, off);
            sc[lane] = e / sum;
        }
        __syncthreads();

        {
            const float* hp = h_s + (size_t)b * 512 + j;
            float p = 0.0f;
#pragma unroll
            for (int t4 = 0; t4 < 8; ++t4) {
                int t = kh * 32 + t4 * 4;
                float4 s4 = *(const float4*)&sc[t];
                p += s4.x * ntload(&hp[(size_t)(t + 0) * 65536])
                   + s4.y * ntload(&hp[(size_t)(t + 1) * 65536])
                   + s4.z * ntload(&hp[(size_t)(t + 2) * 65536])
                   + s4.w * ntload(&hp[(size_t)(t + 3) * 65536]);
            }
            red[kh * 512 + j] = p;
        }
        __syncthreads();
        if (tid < 512) av[tid] = red[tid] + red[512 + tid];
        __syncthreads();

#pragma unroll 1
        for (int g = 0; g < 3; ++g) {
            const uint4* wg = wp3 + g * 512;
            float p = 0.0f;
#pragma unroll 1
            for (int c0 = 0; c0 < 32; c0 += 8) {
                uint4 u[8];
#pragma unroll
                for (int z = 0; z < 8; ++z) u[z] = wg[(size_t)(hq0 + c0 + z) * 1536];
#pragma unroll
                for (int z = 0; z < 8; ++z) {
                    const float* vv = &av[(hq0 + c0 + z) * 8];
                    float4 vA = *(const float4*)vv;
                    float4 vB = *(const float4*)(vv + 4);
                    p += blo(u[z].x) * vA.x + bhi(u[z].x) * vA.y
                       + blo(u[z].y) * vA.z + bhi(u[z].y) * vA.w
                       + blo(u[z].z) * vB.x + bhi(u[z].z) * vB.y
                       + blo(u[z].w) * vB.z + bhi(u[z].w) * vB.w;
                }
            }
            red3[(g * 2 + kh) * 512 + j] = p;
        }
        __syncthreads();
        if (tid < 512) {
            const size_t m = (size_t)k * 128 + b;
            float gi = red3[tid]        + red3[512 + tid]
                     + ntload(&pre_m_h[(m * 3 + 0) * 512 + tid]);
            float gg = red3[1024 + tid] + red3[1536 + tid]
                     + ntload(&pre_m_h[(m * 3 + 1) * 512 + tid]);
            float go = red3[2048 + tid] + red3[2560 + tid]
                     + ntload(&pre_m_h[(m * 3 + 2) * 512 + tid]);
            float cc = fast_sigmoid(gi) * fast_tanh(gg);
            hm[tid]  = fast_sigmoid(go) * fast_tanh(cc);
        }
        __syncthreads();
    }

    if (wv < 3) {
        float p = 0.0f;
#pragma unroll
        for (int u = 0; u < 8; ++u) {
            int h = lane + 64 * u;
            p += hm[h] * fc_w[wv * 512 + h];
        }
#pragma unroll
        for (int off = 32; off; off >>= 1) p += __shfl_xor(p, off);
        if (lane == 0) out[b * 3 + wv] = p + fc_b[wv];
    }
}

extern "C" void kernel_launch(void* const* d_in, const int* in_sizes, int n_in,
                              void* d_out, int out_size, void* d_ws, size_t ws_size,
                              hipStream_t stream)
{
    (void)in_sizes; (void)n_in; (void)out_size;
    const int*   premise    = (const int*)d_in[0];
    const int*   hypothesis = (const int*)d_in[2];
    const float* embed  = (const float*)d_in[4];
    const float* w_e    = (const float*)d_in[5];
    const float* Ws     = (const float*)d_in[6];
    const float* Wt     = (const float*)d_in[7];
    const float* Wm     = (const float*)d_in[8];
    const float* Wih_p  = (const float*)d_in[9];
    const float* bih_p  = (const float*)d_in[10];
    const float* bhh_p  = (const float*)d_in[11];
    const float* Wih_h  = (const float*)d_in[12];
    const float* bih_h  = (const float*)d_in[13];
    const float* bhh_h  = (const float*)d_in[14];
    const float* Wih_m  = (const float*)d_in[15];
    const float* bih_m  = (const float*)d_in[16];
    const float* bhh_m  = (const float*)d_in[17];
    const float* fc_w   = (const float*)d_in[18];
    const float* fc_b   = (const float*)d_in[19];

    float* ws      = (float*)d_ws;
    float* h_s     = ws;                      // 8192*512
    float* h_t     = h_s    + 4194304;        // 8192*512 (aliased by packs)
    float* pre_s   = h_t    + 4194304;
    float* pre_t   = pre_s  + 4194304;
    float* pre_m_h = pre_t  + 4194304;        // 8192*3*512 (+ encoder scratch)
    unsigned* WmT2 = (unsigned*)h_t;          // aliases h_t after last reader
    unsigned* W3t2 = WmT2 + 131072;
    float* outp    = (float*)d_out;
    if (ws_size < (size_t)29556736 * 4) return;

    dim3 blk(256);
    float* P = pre_m_h;                       // encoder preact scratch

    // Phase A (all MFMA)
    mfma_g3_kernel<1><<<dim3(128, 24), blk, 0, stream>>>(
        embed, premise, 300, 300, Wih_p, 300, bih_p, bhh_p, P);
    enc_gates_kernel<<<4096, blk, 0, stream>>>(P, h_s);
    mfma_g3_kernel<1><<<dim3(128, 24), blk, 0, stream>>>(
        embed, hypothesis, 300, 300, Wih_h, 300, bih_h, bhh_h, P);
    enc_gates_kernel<<<4096, blk, 0, stream>>>(P, h_t);
    mfma_nt_kernel<<<dim3(128, 8), blk, 0, stream>>>(h_s, Ws, pre_s);
    mfma_nt_kernel<<<dim3(128, 8), blk, 0, stream>>>(h_t, Wt, pre_t);
    mfma_g3_kernel<0><<<dim3(128, 24), blk, 0, stream>>>(
        h_t, nullptr, 512, 512, Wih_m + 512, 1024, bih_m, bhh_m, pre_m_h);

    // Weight transposes (after h_t's last reader; outputs alias h_t space)
    trans_pack_kernel<<<dim3(8, 4, 1), blk, 0, stream>>>(Wm, 512, 0, WmT2, 512);
    trans_pack_kernel<<<dim3(8, 4, 3), blk, 0, stream>>>(Wih_m, 1024, 1, W3t2, 1536);

    // Phase B (Round-10 verbatim)
    phaseB_kernel<<<dim3(128), dim3(1024), 0, stream>>>(
        pre_s, pre_t, h_s, pre_m_h, WmT2, W3t2, w_e, fc_w, fc_b, outp);
}